// Round 4
// baseline (243.605 us; speedup 1.0000x reference)
//
#include <hip/hip_runtime.h>
#include <hip/hip_bf16.h>
#include <hip/hip_cooperative_groups.h>

namespace cg = cooperative_groups;

#define HID 768

// ---- ws layout ----
// bf16: Abf [2048x768] at 0 (rows 0-511 target, 512-2047 cont)
//       Wbf [2304x768] at short-ofs 1572864 (Wq | Wk | Wv)
// fp32: Q [512x768], K [1536x768], V [1536x768] from float-ofs 1671168
#define WBF_OFF   1572864
#define QKV_OFF   1671168
#define QN        393216
#define KVN       1179648

typedef __bf16 bf16x8 __attribute__((ext_vector_type(8)));
typedef float  f32x4  __attribute__((ext_vector_type(4)));

__device__ __forceinline__ unsigned short f2bf(float f) {
    unsigned u = __builtin_bit_cast(unsigned, f);
    u += 0x7FFFu + ((u >> 16) & 1u);          // RNE
    return (unsigned short)(u >> 16);
}

__device__ __forceinline__ void async_cp16(const void* g, void* l) {
    __builtin_amdgcn_global_load_lds(
        (const __attribute__((address_space(1))) void*)g,
        (__attribute__((address_space(3))) void*)l, 16, 0, 0);
}

// One cooperative launch: phase1 cvt -> grid.sync -> phase2 qkv gemm -> grid.sync -> phase3 finalize
// grid = 512 x 256. LDS 32 KB (BK=64, 2-stage) -> 2 blocks/CU co-resident.
__global__ __launch_bounds__(256) void fused(
    const float4* __restrict__ t4, const float4* __restrict__ c4,
    const float4* __restrict__ wq4, const float4* __restrict__ wk4,
    const float4* __restrict__ wv4,
    const float* __restrict__ bq, const float* __restrict__ bk,
    const float* __restrict__ bv,
    const float* __restrict__ p, const float* __restrict__ hmat,
    const float* __restrict__ g,
    float* __restrict__ wsf, float* __restrict__ out)
{
    cg::grid_group gg = cg::this_grid();
    __shared__ __align__(16) char ldsb[32768];

    unsigned short* bfreg = (unsigned short*)wsf;
    ushort4* abf = (ushort4*)bfreg;
    ushort4* wbf = (ushort4*)(bfreg + WBF_OFF);

    int tid = threadIdx.x;

    // ---------- phase 1: fp32 -> bf16 (grid-stride over 835584 float4 units) ----------
    for (int i = blockIdx.x * 256 + tid; i < 835584; i += 512 * 256) {
        float4 v;
        ushort4* d;
        if (i < 393216) {
            v = (i < 98304) ? t4[i] : c4[i - 98304];
            d = abf + i;
        } else {
            int j = i - 393216;
            v = (j < 147456) ? wq4[j] : (j < 294912 ? wk4[j - 147456] : wv4[j - 294912]);
            d = wbf + j;
        }
        ushort4 o = { f2bf(v.x), f2bf(v.y), f2bf(v.z), f2bf(v.w) };
        *d = o;
    }
    gg.sync();

    // ---------- phase 2: C[rows,768] = A @ W^T + bias, 64x64 tiles, BK=64 2-stage ----------
    const unsigned short* Ab = bfreg;
    const unsigned short* Wb = bfreg + WBF_OFF;
    float* Qf = wsf + QKV_OFF;
    float* Kf = Qf + QN;
    float* Vf = Kf + KVN;

    int lane  = tid & 63;
    int w     = tid >> 6;
    int q     = lane >> 4;          // quad
    int fm    = lane & 15;
    int wm    = (w & 1) * 32, wn = (w >> 1) * 32;
    int srow8 = lane >> 3;          // 0..7 staging sub-row
    int gsw   = (lane & 7) ^ srow8; // XOR-swizzled k-chunk (conflict-free frag reads)

    for (int t = blockIdx.x; t < 672; t += 512) {
        int tt = t;
        const unsigned short *A, *W;
        const float* bias;
        float* C;
        int mtiles;
        if (tt < 96)       {           A = Ab;              W = Wb;              bias = bq; C = Qf; mtiles = 8;  }
        else if (tt < 384) { tt -= 96;  A = Ab + 512 * HID; W = Wb + 768 * HID;  bias = bk; C = Kf; mtiles = 24; }
        else               { tt -= 384; A = Ab + 512 * HID; W = Wb + 1536 * HID; bias = bv; C = Vf; mtiles = 24; }
        int tn = tt / mtiles, tm = tt % mtiles;
        int row0 = tm * 64, col0 = tn * 64;

        // staging ptrs: inst j covers rows j*32 + w*8 + srow8, swizzled chunk gsw
        const unsigned short* gA[2];
        const unsigned short* gB[2];
        #pragma unroll
        for (int j = 0; j < 2; j++) {
            int r = j * 32 + w * 8 + srow8;
            gA[j] = A + (size_t)(row0 + r) * HID + gsw * 8;
            gB[j] = W + (size_t)(col0 + r) * HID + gsw * 8;
        }

        f32x4 acc00 = {0.f, 0.f, 0.f, 0.f};
        f32x4 acc01 = acc00, acc10 = acc00, acc11 = acc00;

        // stage s: A at s*16384, B at s*16384+8192 (row stride 128 B)
        #define STAGE_LOAD(s, kc)                                           \
            {                                                               \
                char* bA_ = ldsb + (s) * 16384;                             \
                char* bB_ = bA_ + 8192;                                     \
                int ko_ = (kc) * 64;                                        \
                _Pragma("unroll")                                           \
                for (int j = 0; j < 2; j++) {                               \
                    async_cp16(gA[j] + ko_, bA_ + (j * 4 + w) * 1024);      \
                    async_cp16(gB[j] + ko_, bB_ + (j * 4 + w) * 1024);      \
                }                                                           \
            }

        __syncthreads();             // prior tile / phase done with LDS
        STAGE_LOAD(0, 0)
        STAGE_LOAD(1, 1)
        __syncthreads();

        #pragma unroll
        for (int c = 0; c < 12; c++) {
            int s = c & 1;
            char* bA = ldsb + s * 16384;
            char* bB = bA + 8192;
            #pragma unroll
            for (int s4 = 0; s4 < 2; s4++) {
                int slot = ((s4 * 4 + q) ^ (fm & 7)) * 16;   // de-swizzle
                bf16x8 af0 = *(const bf16x8*)(bA + (wm + fm) * 128 + slot);
                bf16x8 af1 = *(const bf16x8*)(bA + (wm + 16 + fm) * 128 + slot);
                bf16x8 bf0 = *(const bf16x8*)(bB + (wn + fm) * 128 + slot);
                bf16x8 bf1 = *(const bf16x8*)(bB + (wn + 16 + fm) * 128 + slot);
                acc00 = __builtin_amdgcn_mfma_f32_16x16x32_bf16(af0, bf0, acc00, 0, 0, 0);
                acc01 = __builtin_amdgcn_mfma_f32_16x16x32_bf16(af0, bf1, acc01, 0, 0, 0);
                acc10 = __builtin_amdgcn_mfma_f32_16x16x32_bf16(af1, bf0, acc10, 0, 0, 0);
                acc11 = __builtin_amdgcn_mfma_f32_16x16x32_bf16(af1, bf1, acc11, 0, 0, 0);
            }
            if (c < 10) {
                __syncthreads();          // readers done; drains in-flight loads
                STAGE_LOAD(s, c + 2)
            } else if (c == 10) {
                __syncthreads();          // drain chunk-11 load
            }
        }
        #undef STAGE_LOAD

        // C/D layout (m89/m91): col = lane&15, row = quad*4 + reg
        int crow = row0 + wm + q * 4;
        int ccol = col0 + wn + fm;
        float bb0 = bias[ccol], bb1 = bias[ccol + 16];
        #pragma unroll
        for (int rg = 0; rg < 4; rg++) {
            C[(size_t)(crow + rg)      * HID + ccol]      = acc00[rg] + bb0;
            C[(size_t)(crow + rg)      * HID + ccol + 16] = acc01[rg] + bb1;
            C[(size_t)(crow + 16 + rg) * HID + ccol]      = acc10[rg] + bb0;
            C[(size_t)(crow + 16 + rg) * HID + ccol + 16] = acc11[rg] + bb1;
        }
    }
    gg.sync();

    // ---------- phase 3: per-batch epilogue, b = blockIdx.x ----------
    {
        int b    = blockIdx.x;
        int wv   = tid >> 6;
        float* sred = (float*)ldsb;          // [12][4]
        float* fin  = (float*)ldsb + 64;     // [12]

        const float* qrow = wsf + QKV_OFF + (size_t)b * HID;
        const float* kk   = wsf + QKV_OFF + QN + (size_t)b * 3 * HID;
        const float* vv   = kk + KVN;

        float acc[12];
        #pragma unroll
        for (int i = 0; i < 12; i++) acc[i] = 0.f;

        for (int h0 = tid; h0 < HID; h0 += 256) {
            float qh = qrow[h0];
            float k0 = kk[h0], k1 = kk[HID + h0], k2 = kk[2 * HID + h0];
            float v0 = vv[h0], v1 = vv[HID + h0], v2 = vv[2 * HID + h0];
            acc[0] += p[h0] * qh;
            acc[1] += p[HID + h0] * qh;
            acc[2] += p[2 * HID + h0] * qh;
            float x0 = qh * k0, x1 = qh * k1, x2 = qh * k2;
            const float* h0p = hmat + (size_t)h0 * 3;
            const float* h1p = hmat + (size_t)(HID + h0) * 3;
            const float* h2p = hmat + (size_t)(2 * HID + h0) * 3;
            acc[3] += x0 * h0p[0] + x1 * h1p[0] + x2 * h2p[0];
            acc[4] += x0 * h0p[1] + x1 * h1p[1] + x2 * h2p[1];
            acc[5] += x0 * h0p[2] + x1 * h1p[2] + x2 * h2p[2];
            acc[6]  += v0 * v0; acc[7]  += v0 * v1; acc[8]  += v0 * v2;
            acc[9]  += v1 * v1; acc[10] += v1 * v2; acc[11] += v2 * v2;
        }

        #pragma unroll
        for (int i = 0; i < 12; i++)
            #pragma unroll
            for (int off = 32; off > 0; off >>= 1)
                acc[i] += __shfl_down(acc[i], off);

        __syncthreads();   // LDS reuse after phase 2
        if ((tid & 63) == 0) {
            #pragma unroll
            for (int i = 0; i < 12; i++) sred[i * 4 + wv] = acc[i];
        }
        __syncthreads();
        if (tid < 12) fin[tid] = sred[tid * 4] + sred[tid * 4 + 1] + sred[tid * 4 + 2] + sred[tid * 4 + 3];
        __syncthreads();

        float kern0 = fin[0] + fin[3], kern1 = fin[1] + fin[4], kern2 = fin[2] + fin[5];
        float S00 = fin[6], S01 = fin[7], S02 = fin[8];
        float S11 = fin[9], S12 = fin[10], S22 = fin[11];

        for (int cc = tid; cc < HID; cc += 256) {
            float g0 = g[cc], g1 = g[HID + cc], g2 = g[2 * HID + cc];
            float v0 = vv[cc], v1 = vv[HID + cc], v2 = vv[2 * HID + cc];
            float c0 = S00 * g0 + S01 * g1 + S02 * g2 + v0;
            float c1 = S01 * g0 + S11 * g1 + S12 * g2 + v1;
            float c2 = S02 * g0 + S12 * g1 + S22 * g2 + v2;
            out[(size_t)b * HID + cc] = kern0 * c0 + kern1 * c1 + kern2 * c2;
        }
    }
}

extern "C" void kernel_launch(void* const* d_in, const int* in_sizes, int n_in,
                              void* d_out, int out_size, void* d_ws, size_t ws_size,
                              hipStream_t stream) {
    (void)in_sizes; (void)n_in; (void)out_size; (void)ws_size;
    const float4* t4  = (const float4*)d_in[0];
    const float4* c4  = (const float4*)d_in[1];
    const float4* wq4 = (const float4*)d_in[2];
    const float*  bq  = (const float*)d_in[3];
    const float4* wk4 = (const float4*)d_in[4];
    const float*  bk  = (const float*)d_in[5];
    const float4* wv4 = (const float4*)d_in[6];
    const float*  bv  = (const float*)d_in[7];
    const float*  p   = (const float*)d_in[8];
    const float*  hm  = (const float*)d_in[9];
    const float*  g   = (const float*)d_in[10];
    float* wsf = (float*)d_ws;
    float* out = (float*)d_out;

    void* args[13] = { &t4, &c4, &wq4, &wk4, &wv4, &bq, &bk, &bv,
                       &p, &hm, &g, &wsf, &out };
    hipLaunchCooperativeKernel((const void*)fused, dim3(512), dim3(256),
                               args, 0, stream);
}

// Round 5
// 103.315 us; speedup vs baseline: 2.3579x; 2.3579x over previous
//
#include <hip/hip_runtime.h>
#include <hip/hip_bf16.h>

#define HID 768
#define NB  512
#define NM  3

typedef __bf16 bf16x8 __attribute__((ext_vector_type(8)));
typedef float  f32x4  __attribute__((ext_vector_type(4)));

// ---- ws layout (element offsets) ----
// bf16: Abf [2048x768] at 0 (rows 0-511 target, 512-2047 cont)
//       Wbf [2304x768] at 1572864 (Wq | Wk | Wv)
// fp32: Q [512x768], K [1536x768], V [1536x768] from float ofs 1671168
#define WBF_OFF   1572864
#define QKV_OFF   1671168
#define QN        393216
#define KVN       1179648

__device__ __forceinline__ unsigned short f2bf(float f) {
    unsigned u = __builtin_bit_cast(unsigned, f);
    u += 0x7FFFu + ((u >> 16) & 1u);          // RNE
    return (unsigned short)(u >> 16);
}

__device__ __forceinline__ void async_cp16(const void* g, void* l) {
    __builtin_amdgcn_global_load_lds(
        (const __attribute__((address_space(1))) void*)g,
        (__attribute__((address_space(3))) void*)l, 16, 0, 0);
}

// ---- fp32 -> bf16 conversion, one streaming pass (3264 x 256) ----
__global__ __launch_bounds__(256) void cvt(
    const float4* __restrict__ t, const float4* __restrict__ c,
    const float4* __restrict__ wq, const float4* __restrict__ wk,
    const float4* __restrict__ wv, ushort4* __restrict__ abf,
    ushort4* __restrict__ wbf)
{
    int i = blockIdx.x * 256 + threadIdx.x;
    float4 v;
    ushort4* d;
    if (i < 393216) {
        v = (i < 98304) ? t[i] : c[i - 98304];
        d = abf + i;
    } else {
        int j = i - 393216;
        v = (j < 147456) ? wq[j] : (j < 294912 ? wk[j - 147456] : wv[j - 294912]);
        d = wbf + j;
    }
    ushort4 o = { f2bf(v.x), f2bf(v.y), f2bf(v.z), f2bf(v.w) };
    *d = o;
}

// ---- bf16 MFMA GEMM: C[rows,768] = A @ W^T + bias ----
// 64x64 tiles, BK=128, 2-stage LDS pipeline, XOR-swizzled LDS (conflict-free)
// grid = 96 (Q) + 288 (K) + 288 (V) = 672 blocks, 256 threads
__global__ __launch_bounds__(256) void qkv_gemm(
    const unsigned short* __restrict__ bfp, float* __restrict__ wsf,
    const float* __restrict__ bq, const float* __restrict__ bk,
    const float* __restrict__ bv)
{
    const unsigned short* Ab = bfp;               // 2048x768
    const unsigned short* Wb = bfp + WBF_OFF;     // 2304x768
    float* Qf = wsf + QKV_OFF;
    float* Kf = Qf + QN;
    float* Vf = Kf + KVN;

    int t = blockIdx.x;
    const unsigned short *A, *W;
    const float* bias;
    float* C;
    int mtiles;
    if (t < 96)       {          A = Ab;              W = Wb;              bias = bq; C = Qf; mtiles = 8;  }
    else if (t < 384) { t -= 96;  A = Ab + 512 * HID; W = Wb + 768 * HID;  bias = bk; C = Kf; mtiles = 24; }
    else              { t -= 384; A = Ab + 512 * HID; W = Wb + 1536 * HID; bias = bv; C = Vf; mtiles = 24; }
    int tn = t / mtiles, tm = t % mtiles;
    int row0 = tm * 64, col0 = tn * 64;

    // stage s: A tile at s*32768, B tile at s*32768+16384 (bytes). 64 KB total.
    __shared__ __align__(16) unsigned short lds[32768];
    char* ldsb = (char*)lds;

    int tid  = threadIdx.x;
    int lane = tid & 63;
    int w    = tid >> 6;
    int q    = lane >> 4;        // quad 0..3
    int fm   = lane & 15;

    // Staging: instruction j of wave w covers LDS bytes [j*4096 + w*1024, +1024)
    // -> row r = j*16 + w*4 + q, 16B-slot c = fm. Slot c of row r holds global
    // k-chunk g = c ^ (r&15)  (XOR swizzle => conflict-free frag reads).
    const unsigned short* gA[4];
    const unsigned short* gB[4];
    #pragma unroll
    for (int j = 0; j < 4; j++) {
        int r = j * 16 + w * 4 + q;
        int g = fm ^ (r & 15);
        gA[j] = A + (size_t)(row0 + r) * HID + g * 8;
        gB[j] = W + (size_t)(col0 + r) * HID + g * 8;
    }

    int wm = (w & 1) * 32, wn = (w >> 1) * 32;

    f32x4 acc00 = {0.f, 0.f, 0.f, 0.f};
    f32x4 acc01 = acc00, acc10 = acc00, acc11 = acc00;

    #define STAGE_LOAD(s, kc)                                            \
        {                                                                \
            char* bA_ = ldsb + (s) * 32768;                              \
            char* bB_ = bA_ + 16384;                                     \
            int ko_ = (kc) * 128;                                        \
            _Pragma("unroll")                                            \
            for (int j = 0; j < 4; j++) {                                \
                async_cp16(gA[j] + ko_, bA_ + j * 4096 + w * 1024);      \
                async_cp16(gB[j] + ko_, bB_ + j * 4096 + w * 1024);      \
            }                                                            \
        }

    STAGE_LOAD(0, 0)
    STAGE_LOAD(1, 1)
    __syncthreads();

    #pragma unroll
    for (int c = 0; c < 6; c++) {
        int s = c & 1;
        char* bA = ldsb + s * 32768;
        char* bB = bA + 16384;
        #pragma unroll
        for (int s4 = 0; s4 < 4; s4++) {
            int slot = ((4 * s4 + q) ^ fm) * 16;     // de-swizzle
            bf16x8 af0 = *(const bf16x8*)(bA + (wm + fm) * 256 + slot);
            bf16x8 af1 = *(const bf16x8*)(bA + (wm + 16 + fm) * 256 + slot);
            bf16x8 bf0 = *(const bf16x8*)(bB + (wn + fm) * 256 + slot);
            bf16x8 bf1 = *(const bf16x8*)(bB + (wn + 16 + fm) * 256 + slot);
            acc00 = __builtin_amdgcn_mfma_f32_16x16x32_bf16(af0, bf0, acc00, 0, 0, 0);
            acc01 = __builtin_amdgcn_mfma_f32_16x16x32_bf16(af0, bf1, acc01, 0, 0, 0);
            acc10 = __builtin_amdgcn_mfma_f32_16x16x32_bf16(af1, bf0, acc10, 0, 0, 0);
            acc11 = __builtin_amdgcn_mfma_f32_16x16x32_bf16(af1, bf1, acc11, 0, 0, 0);
        }
        if (c < 4) {
            __syncthreads();            // readers of buf s done; drains prev load
            STAGE_LOAD(s, c + 2)
        } else if (c == 4) {
            __syncthreads();            // drain chunk-5 load before last compute
        }
    }
    #undef STAGE_LOAD

    // C/D layout (m89/m91): col = lane&15, row = (lane>>4)*4 + reg
    int crow = row0 + wm + q * 4;
    int ccol = col0 + wn + fm;
    float bb0 = bias[ccol], bb1 = bias[ccol + 16];
    #pragma unroll
    for (int rg = 0; rg < 4; rg++) {
        C[(size_t)(crow + rg)      * HID + ccol]      = acc00[rg] + bb0;
        C[(size_t)(crow + rg)      * HID + ccol + 16] = acc01[rg] + bb1;
        C[(size_t)(crow + 16 + rg) * HID + ccol]      = acc10[rg] + bb0;
        C[(size_t)(crow + 16 + rg) * HID + ccol + 16] = acc11[rg] + bb1;
    }
}

// ---- per-batch epilogue (512 x 256) ----
__global__ __launch_bounds__(256) void finalize(
    const float* __restrict__ wsf, const float* __restrict__ p,
    const float* __restrict__ hmat, const float* __restrict__ g,
    float* __restrict__ out)
{
    int b    = blockIdx.x;
    int tid  = threadIdx.x;
    int lane = tid & 63;
    int wv   = tid >> 6;

    const float* qrow = wsf + QKV_OFF + (size_t)b * HID;
    const float* kk   = wsf + QKV_OFF + QN + (size_t)b * NM * HID;
    const float* vv   = kk + KVN;

    float acc[12];
    #pragma unroll
    for (int i = 0; i < 12; i++) acc[i] = 0.f;

    for (int h0 = tid; h0 < HID; h0 += 256) {
        float qh = qrow[h0];
        float k0 = kk[h0], k1 = kk[HID + h0], k2 = kk[2 * HID + h0];
        float v0 = vv[h0], v1 = vv[HID + h0], v2 = vv[2 * HID + h0];
        acc[0] += p[h0] * qh;
        acc[1] += p[HID + h0] * qh;
        acc[2] += p[2 * HID + h0] * qh;
        float x0 = qh * k0, x1 = qh * k1, x2 = qh * k2;
        const float* h0p = hmat + (size_t)h0 * 3;
        const float* h1p = hmat + (size_t)(HID + h0) * 3;
        const float* h2p = hmat + (size_t)(2 * HID + h0) * 3;
        acc[3] += x0 * h0p[0] + x1 * h1p[0] + x2 * h2p[0];
        acc[4] += x0 * h0p[1] + x1 * h1p[1] + x2 * h2p[1];
        acc[5] += x0 * h0p[2] + x1 * h1p[2] + x2 * h2p[2];
        acc[6]  += v0 * v0; acc[7]  += v0 * v1; acc[8]  += v0 * v2;
        acc[9]  += v1 * v1; acc[10] += v1 * v2; acc[11] += v2 * v2;
    }

    #pragma unroll
    for (int i = 0; i < 12; i++)
        #pragma unroll
        for (int off = 32; off > 0; off >>= 1)
            acc[i] += __shfl_down(acc[i], off);

    __shared__ float sred[12][4];
    __shared__ float fin[12];
    if (lane == 0) {
        #pragma unroll
        for (int i = 0; i < 12; i++) sred[i][wv] = acc[i];
    }
    __syncthreads();
    if (tid < 12) fin[tid] = sred[tid][0] + sred[tid][1] + sred[tid][2] + sred[tid][3];
    __syncthreads();

    float kern0 = fin[0] + fin[3], kern1 = fin[1] + fin[4], kern2 = fin[2] + fin[5];
    float S00 = fin[6], S01 = fin[7], S02 = fin[8];
    float S11 = fin[9], S12 = fin[10], S22 = fin[11];

    for (int cc = tid; cc < HID; cc += 256) {
        float g0 = g[cc], g1 = g[HID + cc], g2 = g[2 * HID + cc];
        float v0 = vv[cc], v1 = vv[HID + cc], v2 = vv[2 * HID + cc];
        float c0 = S00 * g0 + S01 * g1 + S02 * g2 + v0;
        float c1 = S01 * g0 + S11 * g1 + S12 * g2 + v1;
        float c2 = S02 * g0 + S12 * g1 + S22 * g2 + v2;
        out[(size_t)b * HID + cc] = kern0 * c0 + kern1 * c1 + kern2 * c2;
    }
}

extern "C" void kernel_launch(void* const* d_in, const int* in_sizes, int n_in,
                              void* d_out, int out_size, void* d_ws, size_t ws_size,
                              hipStream_t stream) {
    (void)in_sizes; (void)n_in; (void)out_size; (void)ws_size;
    const float* target = (const float*)d_in[0];
    const float* cont   = (const float*)d_in[1];
    const float* Wq     = (const float*)d_in[2];
    const float* bq     = (const float*)d_in[3];
    const float* Wk     = (const float*)d_in[4];
    const float* bk     = (const float*)d_in[5];
    const float* Wv     = (const float*)d_in[6];
    const float* bv     = (const float*)d_in[7];
    const float* p      = (const float*)d_in[8];
    const float* hmat   = (const float*)d_in[9];
    const float* g      = (const float*)d_in[10];

    unsigned short* bfreg = (unsigned short*)d_ws;
    float* wsf = (float*)d_ws;
    float* out = (float*)d_out;

    cvt<<<3264, 256, 0, stream>>>((const float4*)target, (const float4*)cont,
                                  (const float4*)Wq, (const float4*)Wk, (const float4*)Wv,
                                  (ushort4*)bfreg, (ushort4*)(bfreg + WBF_OFF));
    qkv_gemm<<<672, 256, 0, stream>>>(bfreg, wsf, bq, bk, bv);
    finalize<<<512, 256, 0, stream>>>(wsf, p, hmat, g, out);
}